// Round 9
// baseline (351.656 us; speedup 1.0000x reference)
//
#include <hip/hip_runtime.h>
#include <hip/hip_bf16.h>

// GraphSAGE: N=100000, E=1600000, D=64, L=3.
// bf16 activations, decoupled gather (barrier-free, degree-sorted octets)
// + streaming MFMA GEMM. CSR: 256-node-bucket binning build.

#define D 64
#define KDIM 128
#define TS 64           // node tile per gemm block
#define ASTH 136        // LDS A row stride in bf16 elems (272 B, 16B-aligned)
#define BSH 8           // 256 nodes per bucket
#define BNODES 256
#define ECHUNK 4096     // edges per bin block
#define BCAP 5120       // staging records per bucket (mean 4096 + 16 sigma)

typedef unsigned long long u64;
typedef unsigned short u16;
typedef __attribute__((ext_vector_type(8))) short bf16x8;
typedef __attribute__((ext_vector_type(4))) float f32x4;

__device__ inline u16 f2bf(float f) {
    unsigned u = __float_as_uint(f);
    return (u16)((u + 0x7fffu + ((u >> 16) & 1u)) >> 16);   // RNE
}
__device__ inline void bfx8_to_f(uint4 u, float* f) {
    f[0] = __uint_as_float(u.x << 16); f[1] = __uint_as_float(u.x & 0xffff0000u);
    f[2] = __uint_as_float(u.y << 16); f[3] = __uint_as_float(u.y & 0xffff0000u);
    f[4] = __uint_as_float(u.z << 16); f[5] = __uint_as_float(u.z & 0xffff0000u);
    f[6] = __uint_as_float(u.w << 16); f[7] = __uint_as_float(u.w & 0xffff0000u);
}

// ---- setup: x f32->bf16 convert + W pack, one dispatch -----------------
// W packed to bf16 B-fragment layout:
// flat = l*8192 + kt*2048 + nt*512 + lane*8 + j
// holds W'[k = kt*32 + (lane>>4)*8 + j][n = nt*16 + (lane&15)],
// W'[k][n] = k<64 ? Wl[l][n][k] : Wr[l][n][k-64]
__global__ __launch_bounds__(256) void setup_kernel(
    const float* __restrict__ x, u16* __restrict__ xb, int total8,
    const float* __restrict__ Wl, const float* __restrict__ Wr,
    u16* __restrict__ wpk, int wtotal)
{
    int gid = blockIdx.x * 256 + threadIdx.x;
    if (gid < total8) {
        float4 a = *(const float4*)(x + (size_t)gid * 8);
        float4 b = *(const float4*)(x + (size_t)gid * 8 + 4);
        uint4 o;
        o.x = (unsigned)f2bf(a.x) | ((unsigned)f2bf(a.y) << 16);
        o.y = (unsigned)f2bf(a.z) | ((unsigned)f2bf(a.w) << 16);
        o.z = (unsigned)f2bf(b.x) | ((unsigned)f2bf(b.y) << 16);
        o.w = (unsigned)f2bf(b.z) | ((unsigned)f2bf(b.w) << 16);
        *(uint4*)(xb + (size_t)gid * 8) = o;
    } else {
        int idx = gid - total8;
        if (idx < wtotal) {
            int j    = idx & 7;
            int lane = (idx >> 3) & 63;
            int nt   = (idx >> 9) & 3;
            int kt   = (idx >> 11) & 3;
            int l    = idx >> 13;
            int k = kt * 32 + (lane >> 4) * 8 + j;
            int n = nt * 16 + (lane & 15);
            float v = (k < D) ? Wl[((l * D) + n) * D + k]
                              : Wr[((l * D) + n) * D + (k - D)];
            wpk[idx] = f2bf(v);
        }
    }
}

// ---- CSR build via bucket binning --------------------------------------

__global__ __launch_bounds__(256) void bin_kernel(
    const int* __restrict__ srcp, const int* __restrict__ dstp,
    int* __restrict__ bcnt, u64* __restrict__ staging,
    int nE, int nb)
{
    __shared__ int hist[1024];
    __shared__ int bbase[1024];
    int t = threadIdx.x;
    int e0 = blockIdx.x * ECHUNK;
    for (int i = t; i < nb; i += 256) hist[i] = 0;
    __syncthreads();
    int dcache[16];
#pragma unroll
    for (int j = 0; j < 16; ++j) {
        int e = e0 + j * 256 + t;
        int d = (e < nE) ? dstp[e] : -1;
        dcache[j] = d;
        if (d >= 0) atomicAdd(&hist[d >> BSH], 1);
    }
    __syncthreads();
    for (int i = t; i < nb; i += 256) {
        int c = hist[i];
        bbase[i] = (c > 0) ? atomicAdd(&bcnt[i], c) : 0;
        hist[i] = 0;
    }
    __syncthreads();
#pragma unroll
    for (int j = 0; j < 16; ++j) {
        int e = e0 + j * 256 + t;
        int d = dcache[j];
        if (d >= 0) {
            int b = d >> BSH;
            int pos = bbase[b] + atomicAdd(&hist[b], 1);
            u64 rec = ((u64)(unsigned)(d & (BNODES - 1)) << 32) | (unsigned)srcp[e];
            staging[(size_t)b * BCAP + pos] = rec;
        }
    }
}

// one block per bucket: prefix over bcnt, local deg hist + scan, offs/inv,
// degree-counting-sort -> perm, csr fill.
__global__ __launch_bounds__(256) void bucket_build_kernel(
    const u64* __restrict__ staging, const int* __restrict__ bcnt,
    int* __restrict__ offs, float* __restrict__ inv, int* __restrict__ perm,
    int* __restrict__ csr, int n, int nb, int E)
{
    __shared__ int hist[BNODES];
    __shared__ int loffs[BNODES + 1];
    __shared__ int cur[BNODES];
    __shared__ int dhist[64];
    __shared__ int dbase[64];
    __shared__ int dcur[64];
    __shared__ int sbase;
    int b = blockIdx.x, t = threadIdx.x;
    int n0 = b << BSH;
    int nodes = min(BNODES, n - n0);
    int cnt = bcnt[b];
    const u64* seg = staging + (size_t)b * BCAP;
    // wave 0: prefix sum of bcnt[0..b)
    if (t < 64) {
        int partial = 0;
        for (int i = t; i < b; i += 64) partial += bcnt[i];
#pragma unroll
        for (int off = 32; off > 0; off >>= 1) partial += __shfl_xor(partial, off);
        if (t == 0) sbase = partial;
    }
    for (int i = t; i < nodes; i += 256) { hist[i] = 0; cur[i] = 0; }
    if (t < 64) { dhist[t] = 0; dcur[t] = 0; }
    __syncthreads();
    int gbase = sbase;
    for (int e = t; e < cnt; e += 256) atomicAdd(&hist[(int)(seg[e] >> 32)], 1);
    __syncthreads();
    // degree histogram (clamped to 63) for counting sort
    for (int i = t; i < nodes; i += 256) atomicAdd(&dhist[min(hist[i], 63)], 1);
    // wave 0: exclusive scan of per-node degrees -> loffs
    if (t < 64) {
        int carry = 0;
        for (int base0 = 0; base0 < nodes; base0 += 64) {
            int i = base0 + t;
            int v = (i < nodes) ? hist[i] : 0;
            int inc = v;
#pragma unroll
            for (int off = 1; off < 64; off <<= 1) {
                int v2 = __shfl_up(inc, off);
                if (t >= off) inc += v2;
            }
            if (i < nodes) loffs[i] = carry + (inc - v);
            carry += __shfl(inc, 63);
        }
        if (t == 0) loffs[nodes] = carry;
    }
    __syncthreads();
    // wave 0: exclusive scan of dhist -> dbase
    if (t < 64) {
        int v = dhist[t];
        int inc = v;
#pragma unroll
        for (int off = 1; off < 64; off <<= 1) {
            int v2 = __shfl_up(inc, off);
            if (t >= off) inc += v2;
        }
        dbase[t] = inc - v;
    }
    for (int i = t; i < nodes; i += 256) {
        offs[n0 + i] = gbase + loffs[i];
        inv[n0 + i] = 1.0f / fmaxf((float)hist[i], 1.0f);
    }
    if (b == nb - 1 && t == 0) offs[n] = E;
    __syncthreads();
    // counting-sort scatter: perm position by ascending degree bin
    for (int i = t; i < nodes; i += 256) {
        int bin = min(hist[i], 63);
        int pos = dbase[bin] + atomicAdd(&dcur[bin], 1);
        perm[n0 + pos] = n0 + i;
    }
    // csr fill
    for (int e = t; e < cnt; e += 256) {
        u64 rec = seg[e];
        int dl = (int)(rec >> 32);
        int sv = (int)(rec & 0xffffffffu);
        int pos = loffs[dl] + atomicAdd(&cur[dl], 1);
        csr[gbase + pos] = sv;
    }
}

// ---- gather: barrier-free, perm-ordered octets -------------------------
// 256 thr = 4 waves; each wave: 8 nodes (similar degree), 8 lanes/node,
// 16B chunks, csr prefetched one round ahead. Writes bf16 agg rows.

__global__ __launch_bounds__(256, 6) void gather_kernel(
    const u16* __restrict__ xin, const int* __restrict__ offs,
    const int* __restrict__ csr, const float* __restrict__ inv,
    const int* __restrict__ perm, u16* __restrict__ agg, int n)
{
    const int t = threadIdx.x, w = t >> 6, lane = t & 63;
    const int sub = lane >> 3;     // node within octet
    const int fl  = lane & 7;      // 16B chunk within 128B row
    const int base = lane & 56;
    const int r = (blockIdx.x * 4 + w) * 8 + sub;   // perm position

    int v = -1, s = 0, e = 0;
    float scale = 0.f;
    if (r < n) {
        v = perm[r];
        s = offs[v];
        e = offs[v + 1];
        scale = inv[v];
    }
    float acc[8] = {};
    int idx = 0;
    if (s + fl < e) idx = csr[s + fl];
    while (__any(s < e)) {
        int cnt = e - s;
        cnt = cnt < 0 ? 0 : (cnt > 8 ? 8 : cnt);
        int idxv[8];
#pragma unroll
        for (int j = 0; j < 8; ++j) idxv[j] = __shfl(idx, base + j);
        uint4 rows[8];
#pragma unroll
        for (int j = 0; j < 8; ++j)
            rows[j] = *(const uint4*)(xin + (size_t)idxv[j] * D + fl * 8);
        int s2 = s + 8;
        idx = 0;
        if (s2 + fl < e) idx = csr[s2 + fl];    // prefetch next round
#pragma unroll
        for (int j = 0; j < 8; ++j) {
            float f[8];
            bfx8_to_f(rows[j], f);
            float m = (j < cnt) ? 1.f : 0.f;
#pragma unroll
            for (int q = 0; q < 8; ++q) acc[q] = fmaf(f[q], m, acc[q]);
        }
        s = s2;
    }
    if (v >= 0) {
        uint4 o;
        o.x = (unsigned)f2bf(acc[0] * scale) | ((unsigned)f2bf(acc[1] * scale) << 16);
        o.y = (unsigned)f2bf(acc[2] * scale) | ((unsigned)f2bf(acc[3] * scale) << 16);
        o.z = (unsigned)f2bf(acc[4] * scale) | ((unsigned)f2bf(acc[5] * scale) << 16);
        o.w = (unsigned)f2bf(acc[6] * scale) | ((unsigned)f2bf(acc[7] * scale) << 16);
        *(uint4*)(agg + (size_t)v * D + fl * 8) = o;   // full-line 128B row
    }
}

// ---- gemm: out = relu([agg|x] @ W' + b), streaming MFMA ----------------

template <int WRITE_F32>
__global__ __launch_bounds__(512) void gemm_kernel(
    const u16* __restrict__ agg, const u16* __restrict__ xin,
    const u16* __restrict__ wpk,    // [4][4][64][8] bf16, this layer
    const float* __restrict__ bl,   // [64] f32, this layer
    void* __restrict__ outp, int n)
{
    __shared__ u16 A[TS * ASTH];
    const int t = threadIdx.x, w = t >> 6, lane = t & 63;
    const int v0 = blockIdx.x * TS;

    // stage A: row = agg row (k 0..63) | x row (k 64..127)
    for (int i = t; i < TS * 16; i += 512) {
        int row = i >> 4, c = i & 15;
        int v = v0 + row;
        uint4 val = make_uint4(0, 0, 0, 0);
        if (v < n)
            val = (c < 8) ? *(const uint4*)(agg + (size_t)v * D + c * 8)
                          : *(const uint4*)(xin + (size_t)v * D + (c - 8) * 8);
        *(uint4*)(&A[row * ASTH + c * 8]) = val;
    }
    __syncthreads();

    // wave w: C rows [(w>>1)*16, +16), nt tiles {(w&1)*2, (w&1)*2+1}.
    const int m = lane & 15, quad = lane >> 4;
    const int row16 = (w >> 1) * 16;
    const int ntb = (w & 1) * 2;
    f32x4 cacc[2];
    cacc[0] = (f32x4){0.f, 0.f, 0.f, 0.f};
    cacc[1] = (f32x4){0.f, 0.f, 0.f, 0.f};
#pragma unroll
    for (int kt = 0; kt < 4; ++kt) {
        bf16x8 af = *(const bf16x8*)(&A[(row16 + m) * ASTH + kt * 32 + quad * 8]);
#pragma unroll
        for (int ntl = 0; ntl < 2; ++ntl) {
            bf16x8 bf = *(const bf16x8*)(wpk + (size_t)((kt * 4 + ntb + ntl) * 64 + lane) * 8);
            cacc[ntl] = __builtin_amdgcn_mfma_f32_16x16x32_bf16(af, bf, cacc[ntl], 0, 0, 0);
        }
    }
    // C/D layout: col = lane&15, row = quad*4 + reg.
#pragma unroll
    for (int ntl = 0; ntl < 2; ++ntl) {
        int col = (ntb + ntl) * 16 + m;
        float bias = bl[col];
#pragma unroll
        for (int reg = 0; reg < 4; ++reg) {
            int row = row16 + quad * 4 + reg;
            int vv = v0 + row;
            if (vv < n) {
                float val = fmaxf(cacc[ntl][reg] + bias, 0.f);
                if (WRITE_F32)
                    ((float*)outp)[(size_t)vv * D + col] = val;
                else
                    ((u16*)outp)[(size_t)vv * D + col] = f2bf(val);
            }
        }
    }
}

// ---- launch ------------------------------------------------------------

extern "C" void kernel_launch(void* const* d_in, const int* in_sizes, int n_in,
                              void* d_out, int out_size, void* d_ws, size_t ws_size,
                              hipStream_t stream)
{
    const float* x  = (const float*)d_in[0];
    const float* Wl = (const float*)d_in[1];
    const float* bl = (const float*)d_in[2];
    const float* Wr = (const float*)d_in[3];
    const int*   ei = (const int*)d_in[4];

    const int N = in_sizes[0] / D;
    const int E = in_sizes[4] / 2;
    const int L = in_sizes[1] / (D * D);

    const int* srcp = ei;
    const int* dstp = ei + E;

    const int nbuck = (N + BNODES - 1) >> BSH;

    char* w = (char*)d_ws;
    int* bcnt  = (int*)w;               w += 1024 * sizeof(int);
    int* offs  = (int*)w;               w += (size_t)(N + 1) * sizeof(int);
    w = (char*)(((uintptr_t)w + 15) & ~(uintptr_t)15);
    float* inv = (float*)w;             w += (size_t)N * sizeof(float);
    w = (char*)(((uintptr_t)w + 15) & ~(uintptr_t)15);
    int* perm  = (int*)w;               w += (size_t)N * sizeof(int);
    w = (char*)(((uintptr_t)w + 15) & ~(uintptr_t)15);
    int* csr   = (int*)w;               w += (size_t)E * sizeof(int);
    w = (char*)(((uintptr_t)w + 15) & ~(uintptr_t)15);
    u16* wpk   = (u16*)w;               w += (size_t)L * 8192 * sizeof(u16);
    w = (char*)(((uintptr_t)w + 15) & ~(uintptr_t)15);
    u16* xbf0  = (u16*)w;               w += (size_t)N * D * sizeof(u16);
    w = (char*)(((uintptr_t)w + 15) & ~(uintptr_t)15);
    u16* xbf1  = (u16*)w;               w += (size_t)N * D * sizeof(u16);
    w = (char*)(((uintptr_t)w + 15) & ~(uintptr_t)15);
    u16* xbf2  = (u16*)w;               w += (size_t)N * D * sizeof(u16);
    w = (char*)(((uintptr_t)w + 15) & ~(uintptr_t)15);
    u64* staging = (u64*)w;             // nbuck*BCAP*8 B; dead after build
    u16* aggb = (u16*)staging;          // agg aliases staging (>=12.8 MB)

    hipMemsetAsync(bcnt, 0, 1024 * sizeof(int), stream);

    int total8 = N * D / 8;
    int wtotal = L * 8192;
    setup_kernel<<<(total8 + wtotal + 255) / 256, 256, 0, stream>>>(
        x, xbf0, total8, Wl, Wr, wpk, wtotal);
    bin_kernel<<<(E + ECHUNK - 1) / ECHUNK, 256, 0, stream>>>(srcp, dstp, bcnt, staging, E, nbuck);
    bucket_build_kernel<<<nbuck, 256, 0, stream>>>(staging, bcnt, offs, inv, perm, csr, N, nbuck, E);

    const int ngblk = ((N + 7) / 8 + 3) / 4;     // gather blocks (4 octets each)
    const int nmblk = (N + TS - 1) / TS;
    const u16* xcur = xbf0;
    for (int i = 0; i < L; ++i) {
        const u16* wpl = wpk + (size_t)i * 8192;
        const float* bll = bl + (size_t)i * D;
        gather_kernel<<<ngblk, 256, 0, stream>>>(xcur, offs, csr, inv, perm, aggb, N);
        if (i == L - 1) {
            gemm_kernel<1><<<nmblk, 512, 0, stream>>>(aggb, xcur, wpl, bll, d_out, N);
        } else {
            u16* xdst = (i & 1) ? xbf2 : xbf1;
            gemm_kernel<0><<<nmblk, 512, 0, stream>>>(aggb, xcur, wpl, bll, xdst, N);
            xcur = xdst;
        }
    }
}

// Round 10
// 335.962 us; speedup vs baseline: 1.0467x; 1.0467x over previous
//
#include <hip/hip_runtime.h>
#include <hip/hip_bf16.h>

// GraphSAGE: N=100000, E=1600000, D=64, L=3.
// bf16 activations, MFMA phase-2 (bf16 weights, f32 accum).
// Layer kernel: 512 thr/block, 1 octet (8 nodes) per wave, TWO row-batches
// (16 x 16B gathers) in flight per wave. CSR: bucket-binning build.

#define D 64
#define KDIM 128
#define TS 64           // node tile per block
#define ASTH 136        // LDS A row stride in bf16 elems (272 B, 16B-aligned)
#define BSH 9           // 512 nodes per bucket
#define BNODES 512
#define ECHUNK 8192     // edges per bin block
#define BCAP 12288      // staging records per bucket

typedef unsigned long long u64;
typedef unsigned short u16;
typedef __attribute__((ext_vector_type(8))) short bf16x8;
typedef __attribute__((ext_vector_type(4))) float f32x4;

__device__ inline u16 f2bf(float f) {
    unsigned u = __float_as_uint(f);
    return (u16)((u + 0x7fffu + ((u >> 16) & 1u)) >> 16);   // RNE
}
__device__ inline void bfx8_to_f(uint4 u, float* f) {
    f[0] = __uint_as_float(u.x << 16); f[1] = __uint_as_float(u.x & 0xffff0000u);
    f[2] = __uint_as_float(u.y << 16); f[3] = __uint_as_float(u.y & 0xffff0000u);
    f[4] = __uint_as_float(u.z << 16); f[5] = __uint_as_float(u.z & 0xffff0000u);
    f[6] = __uint_as_float(u.w << 16); f[7] = __uint_as_float(u.w & 0xffff0000u);
}

// ---- x f32 -> bf16 -----------------------------------------------------

__global__ __launch_bounds__(256) void convert_x_kernel(
    const float* __restrict__ x, u16* __restrict__ xb, int total8)
{
    int i = blockIdx.x * 256 + threadIdx.x;
    if (i >= total8) return;
    float4 a = *(const float4*)(x + (size_t)i * 8);
    float4 b = *(const float4*)(x + (size_t)i * 8 + 4);
    uint4 o;
    o.x = (unsigned)f2bf(a.x) | ((unsigned)f2bf(a.y) << 16);
    o.y = (unsigned)f2bf(a.z) | ((unsigned)f2bf(a.w) << 16);
    o.z = (unsigned)f2bf(b.x) | ((unsigned)f2bf(b.y) << 16);
    o.w = (unsigned)f2bf(b.z) | ((unsigned)f2bf(b.w) << 16);
    *(uint4*)(xb + (size_t)i * 8) = o;
}

// ---- CSR build via bucket binning --------------------------------------

__global__ __launch_bounds__(256) void bin_kernel(
    const int* __restrict__ srcp, const int* __restrict__ dstp,
    int* __restrict__ bcnt, u64* __restrict__ staging,
    int nE, int nb)
{
    __shared__ int hist[1024];
    __shared__ int bbase[1024];
    int t = threadIdx.x;
    int e0 = blockIdx.x * ECHUNK;
    for (int i = t; i < nb; i += 256) hist[i] = 0;
    __syncthreads();
    int dcache[32];
#pragma unroll
    for (int j = 0; j < 32; ++j) {
        int e = e0 + j * 256 + t;
        int d = (e < nE) ? dstp[e] : -1;
        dcache[j] = d;
        if (d >= 0) atomicAdd(&hist[d >> BSH], 1);
    }
    __syncthreads();
    for (int i = t; i < nb; i += 256) {
        int c = hist[i];
        bbase[i] = (c > 0) ? atomicAdd(&bcnt[i], c) : 0;
        hist[i] = 0;
    }
    __syncthreads();
#pragma unroll
    for (int j = 0; j < 32; ++j) {
        int e = e0 + j * 256 + t;
        int d = dcache[j];
        if (d >= 0) {
            int b = d >> BSH;
            int pos = bbase[b] + atomicAdd(&hist[b], 1);
            u64 rec = ((u64)(unsigned)(d & (BNODES - 1)) << 32) | (unsigned)srcp[e];
            staging[(size_t)b * BCAP + pos] = rec;
        }
    }
}

// one block per bucket: own prefix over bcnt, local deg hist, local scan,
// offs/inv, csr fill.
__global__ __launch_bounds__(256) void bucket_build_kernel(
    const u64* __restrict__ staging, const int* __restrict__ bcnt,
    int* __restrict__ offs, float* __restrict__ inv,
    int* __restrict__ csr, int n, int nb, int E)
{
    __shared__ int hist[BNODES];
    __shared__ int loffs[BNODES + 1];
    __shared__ int cur[BNODES];
    __shared__ int sbase;
    int b = blockIdx.x, t = threadIdx.x;
    int n0 = b << BSH;
    int nodes = min(BNODES, n - n0);
    int cnt = bcnt[b];
    const u64* seg = staging + (size_t)b * BCAP;
    // wave 0: prefix sum of bcnt[0..b)
    if (t < 64) {
        int partial = 0;
        for (int i = t; i < b; i += 64) partial += bcnt[i];
#pragma unroll
        for (int off = 32; off > 0; off >>= 1) partial += __shfl_xor(partial, off);
        if (t == 0) sbase = partial;
    }
    for (int i = t; i < nodes; i += 256) { hist[i] = 0; cur[i] = 0; }
    __syncthreads();
    int gbase = sbase;
    for (int e = t; e < cnt; e += 256) atomicAdd(&hist[(int)(seg[e] >> 32)], 1);
    __syncthreads();
    if (t < 64) {
        int carry = 0;
        for (int base0 = 0; base0 < nodes; base0 += 64) {
            int i = base0 + t;
            int v = (i < nodes) ? hist[i] : 0;
            int inc = v;
#pragma unroll
            for (int off = 1; off < 64; off <<= 1) {
                int v2 = __shfl_up(inc, off);
                if (t >= off) inc += v2;
            }
            if (i < nodes) loffs[i] = carry + (inc - v);
            carry += __shfl(inc, 63);
        }
        if (t == 0) loffs[nodes] = carry;
    }
    __syncthreads();
    for (int i = t; i < nodes; i += 256) {
        offs[n0 + i] = gbase + loffs[i];
        inv[n0 + i] = 1.0f / fmaxf((float)hist[i], 1.0f);
    }
    if (b == nb - 1 && t == 0) offs[n] = E;
    for (int e = t; e < cnt; e += 256) {
        u64 rec = seg[e];
        int dl = (int)(rec >> 32);
        int sv = (int)(rec & 0xffffffffu);
        int pos = loffs[dl] + atomicAdd(&cur[dl], 1);
        csr[gbase + pos] = sv;
    }
}

// W packed to bf16 B-fragment layout:
// flat = l*8192 + kt*2048 + nt*512 + lane*8 + j
// holds W'[k = kt*32 + (lane>>4)*8 + j][n = nt*16 + (lane&15)],
// W'[k][n] = k<64 ? Wl[l][n][k] : Wr[l][n][k-64]
__global__ void pack_w_kernel(const float* __restrict__ Wl,
                              const float* __restrict__ Wr,
                              u16* __restrict__ wpk, int total)
{
    int idx = blockIdx.x * 256 + threadIdx.x;
    if (idx >= total) return;
    int j    = idx & 7;
    int lane = (idx >> 3) & 63;
    int nt   = (idx >> 9) & 3;
    int kt   = (idx >> 11) & 3;
    int l    = idx >> 13;
    int k = kt * 32 + (lane >> 4) * 8 + j;
    int n = nt * 16 + (lane & 15);
    float v = (k < D) ? Wl[((l * D) + n) * D + k]
                      : Wr[((l * D) + n) * D + (k - D)];
    wpk[idx] = f2bf(v);
}

// ---- fused layer: 2-deep pipelined bf16 gather into LDS, MFMA GEMM ----
// 512 threads = 8 waves; each wave gathers 8 nodes (8 lanes/node, 16B
// chunks); two row-batches (16 gathers, 2 KB) in flight per wave; csr
// indices prefetched two rounds ahead.

template <int WRITE_F32>
__global__ __launch_bounds__(512, 4) void layer_kernel(
    const u16* __restrict__ xin, const int* __restrict__ offs,
    const int* __restrict__ csr, const float* __restrict__ inv,
    const u16* __restrict__ wpk,    // [4][4][64][8] bf16, this layer
    const float* __restrict__ bl,   // [64] f32, this layer
    void* __restrict__ outp, int n)
{
    __shared__ u16 A[TS * ASTH];
    const int t = threadIdx.x, w = t >> 6, lane = t & 63;
    const int sub = lane >> 3;     // node within octet (0..7)
    const int fl  = lane & 7;      // 16B chunk within 128B row
    const int base = lane & 56;    // first lane of my 8-lane group
    const int v0 = blockIdx.x * TS;

    // ---- Phase 1 ----
    const int r = w * 8 + sub;
    const int v = v0 + r;
    int s = 0, e = 0;
    float scale = 0.f;
    uint4 xv = make_uint4(0, 0, 0, 0);
    if (v < n) {
        s = offs[v];
        e = offs[v + 1];
        scale = inv[v];
        xv = *(const uint4*)(xin + (size_t)v * D + fl * 8);
    }
    float acc[8] = {};
    int idxA = 0, idxB = 0;
    if (s + fl < e) idxA = csr[s + fl];
    if (s + 8 + fl < e) idxB = csr[s + 8 + fl];
    while (__any(s < e)) {
        int cA = e - s;      cA = cA < 0 ? 0 : (cA > 8 ? 8 : cA);
        int cB = e - s - 8;  cB = cB < 0 ? 0 : (cB > 8 ? 8 : cB);
        int ivA[8], ivB[8];
#pragma unroll
        for (int j = 0; j < 8; ++j) ivA[j] = __shfl(idxA, base + j);
        uint4 rowsA[8];
#pragma unroll
        for (int j = 0; j < 8; ++j)
            rowsA[j] = *(const uint4*)(xin + (size_t)ivA[j] * D + fl * 8);
#pragma unroll
        for (int j = 0; j < 8; ++j) ivB[j] = __shfl(idxB, base + j);
        uint4 rowsB[8];
#pragma unroll
        for (int j = 0; j < 8; ++j)
            rowsB[j] = *(const uint4*)(xin + (size_t)ivB[j] * D + fl * 8);
        // prefetch csr for the next round pair
        idxA = 0; idxB = 0;
        if (s + 16 + fl < e) idxA = csr[s + 16 + fl];
        if (s + 24 + fl < e) idxB = csr[s + 24 + fl];
        // consume A then B
#pragma unroll
        for (int j = 0; j < 8; ++j) {
            float f[8];
            bfx8_to_f(rowsA[j], f);
            float m = (j < cA) ? 1.f : 0.f;
#pragma unroll
            for (int q = 0; q < 8; ++q) acc[q] = fmaf(f[q], m, acc[q]);
        }
#pragma unroll
        for (int j = 0; j < 8; ++j) {
            float f[8];
            bfx8_to_f(rowsB[j], f);
            float m = (j < cB) ? 1.f : 0.f;
#pragma unroll
            for (int q = 0; q < 8; ++q) acc[q] = fmaf(f[q], m, acc[q]);
        }
        s += 16;
    }
    uint4 o;
    o.x = (unsigned)f2bf(acc[0] * scale) | ((unsigned)f2bf(acc[1] * scale) << 16);
    o.y = (unsigned)f2bf(acc[2] * scale) | ((unsigned)f2bf(acc[3] * scale) << 16);
    o.z = (unsigned)f2bf(acc[4] * scale) | ((unsigned)f2bf(acc[5] * scale) << 16);
    o.w = (unsigned)f2bf(acc[6] * scale) | ((unsigned)f2bf(acc[7] * scale) << 16);
    *(uint4*)(&A[r * ASTH + fl * 8]) = o;          // agg: k in [0,64)
    *(uint4*)(&A[r * ASTH + D + fl * 8]) = xv;     // root: k in [64,128)
    __syncthreads();

    // ---- Phase 2: C[64x64] = A[64x128] x W'[128x64] via MFMA -----------
    // wave w: C rows [(w>>1)*16, +16), nt tiles {(w&1)*2, (w&1)*2+1}.
    const int m = lane & 15, quad = lane >> 4;
    const int row16 = (w >> 1) * 16;
    const int ntb = (w & 1) * 2;
    f32x4 cacc[2];
    cacc[0] = (f32x4){0.f, 0.f, 0.f, 0.f};
    cacc[1] = (f32x4){0.f, 0.f, 0.f, 0.f};
#pragma unroll
    for (int kt = 0; kt < 4; ++kt) {
        bf16x8 af = *(const bf16x8*)(&A[(row16 + m) * ASTH + kt * 32 + quad * 8]);
#pragma unroll
        for (int ntl = 0; ntl < 2; ++ntl) {
            bf16x8 bf = *(const bf16x8*)(wpk + (size_t)((kt * 4 + ntb + ntl) * 64 + lane) * 8);
            cacc[ntl] = __builtin_amdgcn_mfma_f32_16x16x32_bf16(af, bf, cacc[ntl], 0, 0, 0);
        }
    }
    // C/D layout: col = lane&15, row = quad*4 + reg.
#pragma unroll
    for (int ntl = 0; ntl < 2; ++ntl) {
        int col = (ntb + ntl) * 16 + m;
        float bias = bl[col];
#pragma unroll
        for (int reg = 0; reg < 4; ++reg) {
            int row = row16 + quad * 4 + reg;
            int vv = v0 + row;
            if (vv < n) {
                float val = fmaxf(cacc[ntl][reg] + bias, 0.f);
                if (WRITE_F32)
                    ((float*)outp)[(size_t)vv * D + col] = val;
                else
                    ((u16*)outp)[(size_t)vv * D + col] = f2bf(val);
            }
        }
    }
}

// ---- launch ------------------------------------------------------------

extern "C" void kernel_launch(void* const* d_in, const int* in_sizes, int n_in,
                              void* d_out, int out_size, void* d_ws, size_t ws_size,
                              hipStream_t stream)
{
    const float* x  = (const float*)d_in[0];
    const float* Wl = (const float*)d_in[1];
    const float* bl = (const float*)d_in[2];
    const float* Wr = (const float*)d_in[3];
    const int*   ei = (const int*)d_in[4];

    const int N = in_sizes[0] / D;
    const int E = in_sizes[4] / 2;
    const int L = in_sizes[1] / (D * D);

    const int* srcp = ei;
    const int* dstp = ei + E;

    const int nbuck = (N + BNODES - 1) >> BSH;

    char* w = (char*)d_ws;
    int* bcnt  = (int*)w;               w += 1024 * sizeof(int);
    int* offs  = (int*)w;               w += (size_t)(N + 1) * sizeof(int);
    w = (char*)(((uintptr_t)w + 15) & ~(uintptr_t)15);
    float* inv = (float*)w;             w += (size_t)N * sizeof(float);
    w = (char*)(((uintptr_t)w + 15) & ~(uintptr_t)15);
    int* csr   = (int*)w;               w += (size_t)E * sizeof(int);
    w = (char*)(((uintptr_t)w + 15) & ~(uintptr_t)15);
    u16* wpk   = (u16*)w;               w += (size_t)L * 8192 * sizeof(u16);
    w = (char*)(((uintptr_t)w + 15) & ~(uintptr_t)15);
    u16* xbf0  = (u16*)w;               w += (size_t)N * D * sizeof(u16);
    w = (char*)(((uintptr_t)w + 15) & ~(uintptr_t)15);
    u16* xbf1  = (u16*)w;               w += (size_t)N * D * sizeof(u16);
    w = (char*)(((uintptr_t)w + 15) & ~(uintptr_t)15);
    u16* xbf2  = (u16*)w;               w += (size_t)N * D * sizeof(u16);
    w = (char*)(((uintptr_t)w + 15) & ~(uintptr_t)15);
    u64* staging = (u64*)w;

    hipMemsetAsync(bcnt, 0, 1024 * sizeof(int), stream);

    convert_x_kernel<<<(N * D / 8 + 255) / 256, 256, 0, stream>>>(x, xbf0, N * D / 8);
    bin_kernel<<<(E + ECHUNK - 1) / ECHUNK, 256, 0, stream>>>(srcp, dstp, bcnt, staging, E, nbuck);
    bucket_build_kernel<<<nbuck, 256, 0, stream>>>(staging, bcnt, offs, inv, csr, N, nbuck, E);

    int wtotal = L * 8192;
    pack_w_kernel<<<(wtotal + 255) / 256, 256, 0, stream>>>(Wl, Wr, wpk, wtotal);

    const int nblk = (N + TS - 1) / TS;
    const u16* xcur = xbf0;
    for (int i = 0; i < L; ++i) {
        const u16* wpl = wpk + (size_t)i * 8192;
        const float* bll = bl + (size_t)i * D;
        if (i == L - 1) {
            layer_kernel<1><<<nblk, 512, 0, stream>>>(xcur, offs, csr, inv, wpl, bll, d_out, N);
        } else {
            u16* xdst = (i & 1) ? xbf2 : xbf1;
            layer_kernel<0><<<nblk, 512, 0, stream>>>(xcur, offs, csr, inv, wpl, bll, xdst, N);
            xcur = xdst;
        }
    }
}

// Round 11
// 290.180 us; speedup vs baseline: 1.2119x; 1.1578x over previous
//
#include <hip/hip_runtime.h>
#include <hip/hip_bf16.h>

// GraphSAGE: N=100000, E=1600000, D=64, L=3.
// bf16 activations, MFMA phase-2 (bf16 weights, f32 accum).
// Layer kernel: R8 config (512 thr, 1 octet/wave, 1-deep csr prefetch).
// CSR: 256-node-bucket binning build, 391 blocks per pass.

#define D 64
#define KDIM 128
#define TS 64           // node tile per block
#define ASTH 136        // LDS A row stride in bf16 elems (272 B, 16B-aligned)
#define BSH 8           // 256 nodes per bucket
#define BNODES 256
#define ECHUNK 4096     // edges per bin block
#define BCAP 4864       // staging records per bucket (mean 4096 + >10 sigma)

typedef unsigned long long u64;
typedef unsigned short u16;
typedef __attribute__((ext_vector_type(8))) short bf16x8;
typedef __attribute__((ext_vector_type(4))) float f32x4;

__device__ inline u16 f2bf(float f) {
    unsigned u = __float_as_uint(f);
    return (u16)((u + 0x7fffu + ((u >> 16) & 1u)) >> 16);   // RNE
}
__device__ inline void bfx8_to_f(uint4 u, float* f) {
    f[0] = __uint_as_float(u.x << 16); f[1] = __uint_as_float(u.x & 0xffff0000u);
    f[2] = __uint_as_float(u.y << 16); f[3] = __uint_as_float(u.y & 0xffff0000u);
    f[4] = __uint_as_float(u.z << 16); f[5] = __uint_as_float(u.z & 0xffff0000u);
    f[6] = __uint_as_float(u.w << 16); f[7] = __uint_as_float(u.w & 0xffff0000u);
}

// ---- setup: x f32->bf16 convert + W pack, one dispatch -----------------
// W packed to bf16 B-fragment layout:
// flat = l*8192 + kt*2048 + nt*512 + lane*8 + j
// holds W'[k = kt*32 + (lane>>4)*8 + j][n = nt*16 + (lane&15)],
// W'[k][n] = k<64 ? Wl[l][n][k] : Wr[l][n][k-64]
__global__ __launch_bounds__(256) void setup_kernel(
    const float* __restrict__ x, u16* __restrict__ xb, int total8,
    const float* __restrict__ Wl, const float* __restrict__ Wr,
    u16* __restrict__ wpk, int wtotal)
{
    int gid = blockIdx.x * 256 + threadIdx.x;
    if (gid < total8) {
        float4 a = *(const float4*)(x + (size_t)gid * 8);
        float4 b = *(const float4*)(x + (size_t)gid * 8 + 4);
        uint4 o;
        o.x = (unsigned)f2bf(a.x) | ((unsigned)f2bf(a.y) << 16);
        o.y = (unsigned)f2bf(a.z) | ((unsigned)f2bf(a.w) << 16);
        o.z = (unsigned)f2bf(b.x) | ((unsigned)f2bf(b.y) << 16);
        o.w = (unsigned)f2bf(b.z) | ((unsigned)f2bf(b.w) << 16);
        *(uint4*)(xb + (size_t)gid * 8) = o;
    } else {
        int idx = gid - total8;
        if (idx < wtotal) {
            int j    = idx & 7;
            int lane = (idx >> 3) & 63;
            int nt   = (idx >> 9) & 3;
            int kt   = (idx >> 11) & 3;
            int l    = idx >> 13;
            int k = kt * 32 + (lane >> 4) * 8 + j;
            int n = nt * 16 + (lane & 15);
            float v = (k < D) ? Wl[((l * D) + n) * D + k]
                              : Wr[((l * D) + n) * D + (k - D)];
            wpk[idx] = f2bf(v);
        }
    }
}

// ---- CSR build via bucket binning --------------------------------------

__global__ __launch_bounds__(256) void bin_kernel(
    const int* __restrict__ srcp, const int* __restrict__ dstp,
    int* __restrict__ bcnt, u64* __restrict__ staging,
    int nE, int nb)
{
    __shared__ int hist[512];
    __shared__ int bbase[512];
    int t = threadIdx.x;
    int e0 = blockIdx.x * ECHUNK;
    for (int i = t; i < nb; i += 256) hist[i] = 0;
    __syncthreads();
    int dcache[16];
#pragma unroll
    for (int j = 0; j < 16; ++j) {
        int e = e0 + j * 256 + t;
        int d = (e < nE) ? dstp[e] : -1;
        dcache[j] = d;
        if (d >= 0) atomicAdd(&hist[d >> BSH], 1);
    }
    __syncthreads();
    for (int i = t; i < nb; i += 256) {
        int c = hist[i];
        bbase[i] = (c > 0) ? atomicAdd(&bcnt[i], c) : 0;
        hist[i] = 0;
    }
    __syncthreads();
#pragma unroll
    for (int j = 0; j < 16; ++j) {
        int e = e0 + j * 256 + t;
        int d = dcache[j];
        if (d >= 0) {
            int b = d >> BSH;
            int pos = bbase[b] + atomicAdd(&hist[b], 1);
            u64 rec = ((u64)(unsigned)(d & (BNODES - 1)) << 32) | (unsigned)srcp[e];
            staging[(size_t)b * BCAP + pos] = rec;
        }
    }
}

// one block per bucket: own prefix over bcnt, local deg hist, local scan,
// offs/inv, csr fill.
__global__ __launch_bounds__(256) void bucket_build_kernel(
    const u64* __restrict__ staging, const int* __restrict__ bcnt,
    int* __restrict__ offs, float* __restrict__ inv,
    int* __restrict__ csr, int n, int nb, int E)
{
    __shared__ int hist[BNODES];
    __shared__ int loffs[BNODES + 1];
    __shared__ int cur[BNODES];
    __shared__ int sbase;
    int b = blockIdx.x, t = threadIdx.x;
    int n0 = b << BSH;
    int nodes = min(BNODES, n - n0);
    int cnt = bcnt[b];
    const u64* seg = staging + (size_t)b * BCAP;
    // wave 0: prefix sum of bcnt[0..b)
    if (t < 64) {
        int partial = 0;
        for (int i = t; i < b; i += 64) partial += bcnt[i];
#pragma unroll
        for (int off = 32; off > 0; off >>= 1) partial += __shfl_xor(partial, off);
        if (t == 0) sbase = partial;
    }
    for (int i = t; i < nodes; i += 256) { hist[i] = 0; cur[i] = 0; }
    __syncthreads();
    int gbase = sbase;
    for (int e = t; e < cnt; e += 256) atomicAdd(&hist[(int)(seg[e] >> 32)], 1);
    __syncthreads();
    if (t < 64) {
        int carry = 0;
        for (int base0 = 0; base0 < nodes; base0 += 64) {
            int i = base0 + t;
            int v = (i < nodes) ? hist[i] : 0;
            int inc = v;
#pragma unroll
            for (int off = 1; off < 64; off <<= 1) {
                int v2 = __shfl_up(inc, off);
                if (t >= off) inc += v2;
            }
            if (i < nodes) loffs[i] = carry + (inc - v);
            carry += __shfl(inc, 63);
        }
        if (t == 0) loffs[nodes] = carry;
    }
    __syncthreads();
    for (int i = t; i < nodes; i += 256) {
        offs[n0 + i] = gbase + loffs[i];
        inv[n0 + i] = 1.0f / fmaxf((float)hist[i], 1.0f);
    }
    if (b == nb - 1 && t == 0) offs[n] = E;
    for (int e = t; e < cnt; e += 256) {
        u64 rec = seg[e];
        int dl = (int)(rec >> 32);
        int sv = (int)(rec & 0xffffffffu);
        int pos = loffs[dl] + atomicAdd(&cur[dl], 1);
        csr[gbase + pos] = sv;
    }
}

// ---- fused layer: pipelined bf16 gather into LDS, MFMA GEMM -----------
// 512 threads = 8 waves; each wave gathers 8 nodes (8 lanes/node, 16B
// chunks); csr indices prefetched one round ahead.  (R8 config.)

template <int WRITE_F32>
__global__ __launch_bounds__(512, 6) void layer_kernel(
    const u16* __restrict__ xin, const int* __restrict__ offs,
    const int* __restrict__ csr, const float* __restrict__ inv,
    const u16* __restrict__ wpk,    // [4][4][64][8] bf16, this layer
    const float* __restrict__ bl,   // [64] f32, this layer
    void* __restrict__ outp, int n)
{
    __shared__ u16 A[TS * ASTH];
    const int t = threadIdx.x, w = t >> 6, lane = t & 63;
    const int sub = lane >> 3;     // node within octet (0..7)
    const int fl  = lane & 7;      // 16B chunk within 128B row
    const int base = lane & 56;    // first lane of my 8-lane group
    const int v0 = blockIdx.x * TS;

    // ---- Phase 1: 8 nodes per wave, csr prefetched one round ahead ----
    const int r = w * 8 + sub;
    const int v = v0 + r;
    int s = 0, e = 0;
    float scale = 0.f;
    uint4 xv = make_uint4(0, 0, 0, 0);
    if (v < n) {
        s = offs[v];
        e = offs[v + 1];
        scale = inv[v];
        xv = *(const uint4*)(xin + (size_t)v * D + fl * 8);
    }
    float acc[8] = {};
    int idx = 0;
    if (s + fl < e) idx = csr[s + fl];
    while (__any(s < e)) {
        int cnt = e - s;
        cnt = cnt < 0 ? 0 : (cnt > 8 ? 8 : cnt);
        int idxv[8];
#pragma unroll
        for (int j = 0; j < 8; ++j) idxv[j] = __shfl(idx, base + j);
        uint4 rows[8];
#pragma unroll
        for (int j = 0; j < 8; ++j)
            rows[j] = *(const uint4*)(xin + (size_t)idxv[j] * D + fl * 8);
        int s2 = s + 8;
        idx = 0;
        if (s2 + fl < e) idx = csr[s2 + fl];    // prefetch next round
#pragma unroll
        for (int j = 0; j < 8; ++j) {
            float f[8];
            bfx8_to_f(rows[j], f);
            float m = (j < cnt) ? 1.f : 0.f;
#pragma unroll
            for (int q = 0; q < 8; ++q) acc[q] = fmaf(f[q], m, acc[q]);
        }
        s = s2;
    }
    uint4 o;
    o.x = (unsigned)f2bf(acc[0] * scale) | ((unsigned)f2bf(acc[1] * scale) << 16);
    o.y = (unsigned)f2bf(acc[2] * scale) | ((unsigned)f2bf(acc[3] * scale) << 16);
    o.z = (unsigned)f2bf(acc[4] * scale) | ((unsigned)f2bf(acc[5] * scale) << 16);
    o.w = (unsigned)f2bf(acc[6] * scale) | ((unsigned)f2bf(acc[7] * scale) << 16);
    *(uint4*)(&A[r * ASTH + fl * 8]) = o;          // agg: k in [0,64)
    *(uint4*)(&A[r * ASTH + D + fl * 8]) = xv;     // root: k in [64,128)
    __syncthreads();

    // ---- Phase 2: C[64x64] = A[64x128] x W'[128x64] via MFMA -----------
    // wave w: C rows [(w>>1)*16, +16), nt tiles {(w&1)*2, (w&1)*2+1}.
    const int m = lane & 15, quad = lane >> 4;
    const int row16 = (w >> 1) * 16;
    const int ntb = (w & 1) * 2;
    f32x4 cacc[2];
    cacc[0] = (f32x4){0.f, 0.f, 0.f, 0.f};
    cacc[1] = (f32x4){0.f, 0.f, 0.f, 0.f};
#pragma unroll
    for (int kt = 0; kt < 4; ++kt) {
        bf16x8 af = *(const bf16x8*)(&A[(row16 + m) * ASTH + kt * 32 + quad * 8]);
#pragma unroll
        for (int ntl = 0; ntl < 2; ++ntl) {
            bf16x8 bf = *(const bf16x8*)(wpk + (size_t)((kt * 4 + ntb + ntl) * 64 + lane) * 8);
            cacc[ntl] = __builtin_amdgcn_mfma_f32_16x16x32_bf16(af, bf, cacc[ntl], 0, 0, 0);
        }
    }
    // C/D layout: col = lane&15, row = quad*4 + reg.
#pragma unroll
    for (int ntl = 0; ntl < 2; ++ntl) {
        int col = (ntb + ntl) * 16 + m;
        float bias = bl[col];
#pragma unroll
        for (int reg = 0; reg < 4; ++reg) {
            int row = row16 + quad * 4 + reg;
            int vv = v0 + row;
            if (vv < n) {
                float val = fmaxf(cacc[ntl][reg] + bias, 0.f);
                if (WRITE_F32)
                    ((float*)outp)[(size_t)vv * D + col] = val;
                else
                    ((u16*)outp)[(size_t)vv * D + col] = f2bf(val);
            }
        }
    }
}

// ---- launch ------------------------------------------------------------

extern "C" void kernel_launch(void* const* d_in, const int* in_sizes, int n_in,
                              void* d_out, int out_size, void* d_ws, size_t ws_size,
                              hipStream_t stream)
{
    const float* x  = (const float*)d_in[0];
    const float* Wl = (const float*)d_in[1];
    const float* bl = (const float*)d_in[2];
    const float* Wr = (const float*)d_in[3];
    const int*   ei = (const int*)d_in[4];

    const int N = in_sizes[0] / D;
    const int E = in_sizes[4] / 2;
    const int L = in_sizes[1] / (D * D);

    const int* srcp = ei;
    const int* dstp = ei + E;

    const int nbuck = (N + BNODES - 1) >> BSH;   // 391 for N=100000

    char* w = (char*)d_ws;
    int* bcnt  = (int*)w;               w += 512 * sizeof(int);
    int* offs  = (int*)w;               w += (size_t)(N + 1) * sizeof(int);
    w = (char*)(((uintptr_t)w + 15) & ~(uintptr_t)15);
    float* inv = (float*)w;             w += (size_t)N * sizeof(float);
    w = (char*)(((uintptr_t)w + 15) & ~(uintptr_t)15);
    int* csr   = (int*)w;               w += (size_t)E * sizeof(int);
    w = (char*)(((uintptr_t)w + 15) & ~(uintptr_t)15);
    u16* wpk   = (u16*)w;               w += (size_t)L * 8192 * sizeof(u16);
    w = (char*)(((uintptr_t)w + 15) & ~(uintptr_t)15);
    u16* xbf0  = (u16*)w;               w += (size_t)N * D * sizeof(u16);
    w = (char*)(((uintptr_t)w + 15) & ~(uintptr_t)15);
    u16* xbf1  = (u16*)w;               w += (size_t)N * D * sizeof(u16);
    w = (char*)(((uintptr_t)w + 15) & ~(uintptr_t)15);
    u16* xbf2  = (u16*)w;               w += (size_t)N * D * sizeof(u16);
    w = (char*)(((uintptr_t)w + 15) & ~(uintptr_t)15);
    u64* staging = (u64*)w;

    hipMemsetAsync(bcnt, 0, 512 * sizeof(int), stream);

    int total8 = N * D / 8;
    int wtotal = L * 8192;
    setup_kernel<<<(total8 + wtotal + 255) / 256, 256, 0, stream>>>(
        x, xbf0, total8, Wl, Wr, wpk, wtotal);
    bin_kernel<<<(E + ECHUNK - 1) / ECHUNK, 256, 0, stream>>>(srcp, dstp, bcnt, staging, E, nbuck);
    bucket_build_kernel<<<nbuck, 256, 0, stream>>>(staging, bcnt, offs, inv, csr, N, nbuck, E);

    const int nblk = (N + TS - 1) / TS;
    const u16* xcur = xbf0;
    for (int i = 0; i < L; ++i) {
        const u16* wpl = wpk + (size_t)i * 8192;
        const float* bll = bl + (size_t)i * D;
        if (i == L - 1) {
            layer_kernel<1><<<nblk, 512, 0, stream>>>(xcur, offs, csr, inv, wpl, bll, d_out, N);
        } else {
            u16* xdst = (i & 1) ? xbf2 : xbf1;
            layer_kernel<0><<<nblk, 512, 0, stream>>>(xcur, offs, csr, inv, wpl, bll, xdst, N);
            xcur = xdst;
        }
    }
}